// Round 6
// baseline (349.400 us; speedup 1.0000x reference)
//
#include <hip/hip_runtime.h>
#include <stdint.h>

typedef __bf16 bf16x8 __attribute__((ext_vector_type(8)));
typedef __bf16 bf16x4 __attribute__((ext_vector_type(4)));
typedef float f32x4 __attribute__((ext_vector_type(4)));
typedef float f32x16 __attribute__((ext_vector_type(16)));

static __device__ __forceinline__ unsigned short f2bf(float f) {
  unsigned u = __builtin_bit_cast(unsigned, f);
  u += 0x7fffu + ((u >> 16) & 1u);   // RNE
  return (unsigned short)(u >> 16);
}

static __device__ __forceinline__ unsigned short bfu(float x) {
  __bf16 b = (__bf16)x;
  return __builtin_bit_cast(unsigned short, b);
}

static __device__ __forceinline__ unsigned cvtpk(float lo, float hi) {
  unsigned r;
  asm("v_cvt_pk_bf16_f32 %0, %1, %2" : "=v"(r) : "v"(lo), "v"(hi));
  return r;
}

// (x, y) <- swap: x = lane<32 ? a : partner's b ; y = lane<32 ? partner's a : b
static __device__ __forceinline__ void plswap(unsigned a, unsigned b,
                                              unsigned& x, unsigned& y) {
#if __has_builtin(__builtin_amdgcn_permlane32_swap)
  auto r = __builtin_amdgcn_permlane32_swap((int)a, (int)b, false, false);
  x = (unsigned)r[0];
  y = (unsigned)r[1];
#else
  unsigned ap = (unsigned)__shfl_xor((int)a, 32);
  unsigned bp = (unsigned)__shfl_xor((int)b, 32);
  const bool lo = (threadIdx.x & 32) == 0;
  x = lo ? a : bp;
  y = lo ? ap : b;
#endif
}

#if __has_builtin(__builtin_amdgcn_exp2f)
#define EXP2(x) __builtin_amdgcn_exp2f(x)
#else
#define EXP2(x) __expf(0.69314718055994531f * (x))
#endif

static __device__ __forceinline__ void gload_lds16(const void* g, void* l) {
  __builtin_amdgcn_global_load_lds(
      (const __attribute__((address_space(1))) unsigned int*)(uintptr_t)g,
      (__attribute__((address_space(3))) unsigned int*)(uintptr_t)l, 16, 0, 0);
}

// ------------------------- fused fp32 -> bf16 convert (all 7 tensors) ----
#define BIGU 2097152
#define WU   262144
__global__ __launch_bounds__(256) void cvt_all(const float* __restrict__ q,  const float* __restrict__ k,
                                               const float* __restrict__ v,  const float* __restrict__ wq,
                                               const float* __restrict__ wk, const float* __restrict__ wv,
                                               const float* __restrict__ wo, ushort4* __restrict__ dst) {
  int u = blockIdx.x * 256 + threadIdx.x;
  const float4* src;
  if (u < BIGU)            src = (const float4*)q + u;
  else if (u < 2 * BIGU)   src = (const float4*)k + (u - BIGU);
  else if (u < 3 * BIGU)   src = (const float4*)v + (u - 2 * BIGU);
  else {
    int r = u - 3 * BIGU;
    if (r < WU)            src = (const float4*)wq + r;
    else if (r < 2 * WU)   src = (const float4*)wk + (r - WU);
    else if (r < 3 * WU)   src = (const float4*)wv + (r - 2 * WU);
    else                   src = (const float4*)wo + (r - 3 * WU);
  }
  float4 f = *src;
  ushort4 o;
  o.x = f2bf(f.x); o.y = f2bf(f.y); o.z = f2bf(f.z); o.w = f2bf(f.w);
  dst[u] = o;
}

// ------------------------- GEMM: C[M,N] = A[M,K] @ W[N,K]^T + bias ------
#define GM 8192
#define GN 1024
#define GK 1024

template <bool OUTF32, bool TRIPLE>
__global__ __launch_bounds__(256, 2) void gemm_bt(const unsigned short* __restrict__ A0,
                                                  const unsigned short* __restrict__ W0,
                                                  const float* __restrict__ bias0,
                                                  const float* __restrict__ bias1,
                                                  const float* __restrict__ bias2,
                                                  void* __restrict__ Cout) {
  __shared__ unsigned short As[2][128 * 64];
  __shared__ unsigned short Bs[2][128 * 64];
  const int z = TRIPLE ? blockIdx.z : 0;
  const unsigned short* A  = A0 + (size_t)z * ((size_t)GM * GK);
  const unsigned short* Bw = W0 + (size_t)z * ((size_t)GN * GK);
  const float* bias = TRIPLE ? (z == 0 ? bias0 : (z == 1 ? bias1 : bias2)) : bias0;

  const int tid = threadIdx.x;
  const int w = tid >> 6;
  const int lane = tid & 63;
  const int lq = lane & 15;
  const int g = lane >> 4;
  const int bm = blockIdx.y * 128;
  const int bn = blockIdx.x * 128;
  const int srow = lane >> 3;
  const int schunk = (lane & 7) ^ srow;
  const int wrow = (w >> 1) * 64;
  const int wcol = (w & 1) * 64;

  f32x4 acc[4][4] = {};

#define STAGE(ktv, bufv)                                                                   \
  do {                                                                                     \
    _Pragma("unroll") for (int j = 0; j < 4; ++j) {                                        \
      const int r0 = w * 32 + j * 8;                                                       \
      gload_lds16(A  + (size_t)(bm + r0 + srow) * GK + (ktv) * 64 + schunk * 8,            \
                  &As[bufv][r0 * 64]);                                                     \
      gload_lds16(Bw + (size_t)(bn + r0 + srow) * GK + (ktv) * 64 + schunk * 8,            \
                  &Bs[bufv][r0 * 64]);                                                     \
    }                                                                                      \
  } while (0)

  STAGE(0, 0);
  __syncthreads();

  for (int kt = 0; kt < GK / 64; ++kt) {
    const int cur = kt & 1;
    if (kt < GK / 64 - 1) STAGE(kt + 1, cur ^ 1);

#pragma unroll
    for (int kk = 0; kk < 2; ++kk) {
      bf16x8 af[4], bfv[4];
#pragma unroll
      for (int mt = 0; mt < 4; ++mt) {
        int m = wrow + mt * 16 + lq;
        af[mt] = *(const bf16x8*)&As[cur][m * 64 + ((kk * 32 + g * 8) ^ ((m & 7) << 3))];
      }
#pragma unroll
      for (int nt = 0; nt < 4; ++nt) {
        int n = wcol + nt * 16 + lq;
        bfv[nt] = *(const bf16x8*)&Bs[cur][n * 64 + ((kk * 32 + g * 8) ^ ((n & 7) << 3))];
      }
#pragma unroll
      for (int mt = 0; mt < 4; ++mt)
#pragma unroll
        for (int nt = 0; nt < 4; ++nt)
          acc[mt][nt] = __builtin_amdgcn_mfma_f32_16x16x32_bf16(af[mt], bfv[nt], acc[mt][nt], 0, 0, 0);
    }
    __syncthreads();
  }
#undef STAGE

  float bvs[4];
#pragma unroll
  for (int nt = 0; nt < 4; ++nt) bvs[nt] = bias[bn + wcol + nt * 16 + lq];

#pragma unroll
  for (int mt = 0; mt < 4; ++mt) {
#pragma unroll
    for (int nt = 0; nt < 4; ++nt) {
#pragma unroll
      for (int r = 0; r < 4; ++r) {
        int m = bm + wrow + mt * 16 + g * 4 + r;
        int n = bn + wcol + nt * 16 + lq;
        float v = acc[mt][nt][r] + bvs[nt];
        if (OUTF32) ((float*)Cout)[(size_t)m * GN + n] = v;
        else ((unsigned short*)Cout)[(size_t)z * ((size_t)GM * GN) + (size_t)m * GN + n] = f2bf(v);
      }
    }
  }
}

// ------------------------- flash attention v4: 32x32 MFMA, in-reg softmax -
// grid (16 q-tiles of 128 rows, 64 bh), 256 threads = 4 waves, each wave one
// 32-q tile. KVB=64 staged double-buffered (K row-swizzled [64][64]; V
// tr16-subtiled); per-32-key-chunk online softmax entirely in registers:
// C(32x32) regs -> cvt_pk_bf16 + permlane32_swap builds the PV B-fragment
// directly (no P LDS round trip).
#define TRRD(dst, off) \
  asm volatile("ds_read_b64_tr_b16 %0, %1 offset:" off \
               : "=v"(dst) \
               : "v"((const __attribute__((address_space(3))) unsigned short*)(uintptr_t)vb))

__global__ __launch_bounds__(256, 4) void attn_fwd(const unsigned short* __restrict__ Qp,
                                                   const unsigned short* __restrict__ Kp,
                                                   const unsigned short* __restrict__ Vp,
                                                   unsigned short* __restrict__ Op) {
  __shared__ unsigned short Ks[2][4096];    // [key][d] row-swizzled, 8KB each
  __shared__ unsigned short Vs[2][4096];    // [key/4][d/16][4][16] subtiled
  const int tid = threadIdx.x;
  const int w = tid >> 6;
  const int lane = tid & 63;
  const int q32 = lane & 31;
  const int l5 = lane >> 5;
  const int qt = blockIdx.x;
  const int bh = blockIdx.y;
  const int b = bh >> 4;
  const int h = bh & 15;
  const size_t rowbase = (size_t)b * 2048;
  const int hcol = h * 64;

  const int c0 = w * 2, c1 = w * 2 + 1;
  const int srow = lane >> 3;
  const int schunk = (lane & 7) ^ srow;
  const int vkeyl = (lane >> 5) * 4 + ((lane >> 1) & 3);
  const int vd0   = ((lane >> 3) & 3) * 16 + (lane & 1) * 8;

  const unsigned short* kq = Kp + rowbase * 1024 + hcol;
  const unsigned short* vq = Vp + rowbase * 1024 + hcol;

  // Q B-fragments: lane = (col q, k-rows ks*16 + l5*8 .. +7)
  const int qrow = qt * 128 + w * 32 + q32;
  bf16x8 qf[4];
#pragma unroll
  for (int ks = 0; ks < 4; ++ks)
    qf[ks] = *(const bf16x8*)&Qp[(rowbase + qrow) * 1024 + hcol + ks * 16 + l5 * 8];

  const float ks2 = 0.125f * 1.44269504088896f;  // scale * log2(e)
  float mreg = -1e30f, lsum = 0.f;
  f32x16 oa[2] = {};                             // O^T: dt -> d = dt*32 + C-row, q = q32

  const int rbase = q32 * 64;
  const int kxor = (lane & 7) << 3;
  int coff[4];
#pragma unroll
  for (int ks = 0; ks < 4; ++ks) coff[ks] = (ks * 16 + l5 * 8) ^ kxor;
  const int vboff = l5 * 512 + ((lane >> 4) & 1) * 64 + ((lane >> 2) & 3) * 16 + (lane & 3) * 4;

  // prologue: stage tile 0 into buf 0
  gload_lds16(kq + (size_t)(c0 * 8 + srow) * 1024 + schunk * 8, &Ks[0][c0 * 512]);
  gload_lds16(kq + (size_t)(c1 * 8 + srow) * 1024 + schunk * 8, &Ks[0][c1 * 512]);
  gload_lds16(vq + (size_t)(c0 * 8 + vkeyl) * 1024 + vd0, &Vs[0][c0 * 512]);
  gload_lds16(vq + (size_t)(c1 * 8 + vkeyl) * 1024 + vd0, &Vs[0][c1 * 512]);
  __syncthreads();

  for (int j = 0; j < 32; ++j) {
    const int cur = j & 1;
    if (j < 31) {   // prefetch next tile into other buffer
      const size_t so = (size_t)(j + 1) * 64 * 1024;
      gload_lds16(kq + so + (size_t)(c0 * 8 + srow) * 1024 + schunk * 8, &Ks[cur ^ 1][c0 * 512]);
      gload_lds16(kq + so + (size_t)(c1 * 8 + srow) * 1024 + schunk * 8, &Ks[cur ^ 1][c1 * 512]);
      gload_lds16(vq + so + (size_t)(c0 * 8 + vkeyl) * 1024 + vd0, &Vs[cur ^ 1][c0 * 512]);
      gload_lds16(vq + so + (size_t)(c1 * 8 + vkeyl) * 1024 + vd0, &Vs[cur ^ 1][c1 * 512]);
    }

#pragma unroll
    for (int kt = 0; kt < 2; ++kt) {
      // ---- QK^T: S^T[key 32][q 32] = sum_ks mfma(K-frag, Q-frag)
      f32x16 c = {};
      __builtin_amdgcn_s_setprio(1);
#pragma unroll
      for (int ks = 0; ks < 4; ++ks) {
        bf16x8 kf = *(const bf16x8*)&Ks[cur][kt * 2048 + rbase + coff[ks]];
        c = __builtin_amdgcn_mfma_f32_32x32x16_bf16(kf, qf[ks], c, 0, 0, 0);
      }
      __builtin_amdgcn_s_setprio(0);

      // ---- V^T fragments via hw transpose read (issue early, wait later)
      const unsigned short* vb = &Vs[cur][kt * 2048 + vboff];
      bf16x4 T[8];
      TRRD(T[0], "0");    TRRD(T[1], "512");
      TRRD(T[2], "256");  TRRD(T[3], "768");
      TRRD(T[4], "2048"); TRRD(T[5], "2560");
      TRRD(T[6], "2304"); TRRD(T[7], "2816");

      // ---- row-max over this 32-key chunk (regs + partner lane)
      float a0 = fmaxf(c[0], c[1]),   a1 = fmaxf(c[2], c[3]);
      float a2 = fmaxf(c[4], c[5]),   a3 = fmaxf(c[6], c[7]);
      float a4 = fmaxf(c[8], c[9]),   a5 = fmaxf(c[10], c[11]);
      float a6 = fmaxf(c[12], c[13]), a7 = fmaxf(c[14], c[15]);
      a0 = fmaxf(a0, a1); a2 = fmaxf(a2, a3); a4 = fmaxf(a4, a5); a6 = fmaxf(a6, a7);
      a0 = fmaxf(a0, a2); a4 = fmaxf(a4, a6);
      float tm = fmaxf(a0, a4);
      tm = fmaxf(tm, __shfl_xor(tm, 32));

      // ---- defer-max (THR=64 raw == 8 scaled)
      if (!__all(tm - mreg <= 64.f)) {
        float n = fmaxf(mreg, tm);
        float cr = EXP2(ks2 * (mreg - n));
        lsum *= cr;
        oa[0] *= cr; oa[1] *= cr;
        mreg = n;
      }
      const float mk = mreg * ks2;
      float p[16];
#pragma unroll
      for (int r = 0; r < 16; ++r) p[r] = EXP2(__builtin_fmaf(c[r], ks2, -mk));
      float s0 = (p[0] + p[1]) + (p[2] + p[3]);
      float s1 = (p[4] + p[5]) + (p[6] + p[7]);
      float s2 = (p[8] + p[9]) + (p[10] + p[11]);
      float s3 = (p[12] + p[13]) + (p[14] + p[15]);
      lsum += (s0 + s1) + (s2 + s3);

      asm volatile("s_waitcnt lgkmcnt(0)" ::: "memory");
      __builtin_amdgcn_sched_barrier(0);

      // ---- pack P -> B-frag (cvt_pk + permlane32_swap) and PV MFMA
      __builtin_amdgcn_s_setprio(1);
#pragma unroll
      for (int t2 = 0; t2 < 2; ++t2) {
        unsigned pA0 = cvtpk(p[8 * t2 + 0], p[8 * t2 + 1]);
        unsigned pA1 = cvtpk(p[8 * t2 + 2], p[8 * t2 + 3]);
        unsigned pB0 = cvtpk(p[8 * t2 + 4], p[8 * t2 + 5]);
        unsigned pB1 = cvtpk(p[8 * t2 + 6], p[8 * t2 + 7]);
        unsigned w0, w1, w2, w3;
        plswap(pA0, pB0, w0, w2);
        plswap(pA1, pB1, w1, w3);
        uint4 wv; wv.x = w0; wv.y = w1; wv.z = w2; wv.w = w3;
        bf16x8 pf = __builtin_bit_cast(bf16x8, wv);
        bf16x8 vf0 = __builtin_shufflevector(T[t2 * 4 + 0], T[t2 * 4 + 1], 0, 1, 2, 3, 4, 5, 6, 7);
        oa[0] = __builtin_amdgcn_mfma_f32_32x32x16_bf16(vf0, pf, oa[0], 0, 0, 0);
        bf16x8 vf1 = __builtin_shufflevector(T[t2 * 4 + 2], T[t2 * 4 + 3], 0, 1, 2, 3, 4, 5, 6, 7);
        oa[1] = __builtin_amdgcn_mfma_f32_32x32x16_bf16(vf1, pf, oa[1], 0, 0, 0);
      }
      __builtin_amdgcn_s_setprio(0);
    }
    __syncthreads();
  }

  // ---- epilogue
  lsum += __shfl_xor(lsum, 32);
  const float inv = 1.0f / lsum;
#pragma unroll
  for (int dt = 0; dt < 2; ++dt) {
#pragma unroll
    for (int jj = 0; jj < 4; ++jj) {
      ushort4 pk;
      pk.x = bfu(oa[dt][4 * jj + 0] * inv);
      pk.y = bfu(oa[dt][4 * jj + 1] * inv);
      pk.z = bfu(oa[dt][4 * jj + 2] * inv);
      pk.w = bfu(oa[dt][4 * jj + 3] * inv);
      const int d0 = dt * 32 + 8 * jj + 4 * l5;
      *(ushort4*)&Op[(rowbase + qrow) * 1024 + hcol + d0] = pk;
    }
  }
}

// ------------------------- launcher --------------------------------------
extern "C" void kernel_launch(void* const* d_in, const int* in_sizes, int n_in,
                              void* d_out, int out_size, void* d_ws, size_t ws_size,
                              hipStream_t stream) {
  const float* q  = (const float*)d_in[0];
  const float* k  = (const float*)d_in[1];
  const float* v  = (const float*)d_in[2];
  const float* Wq = (const float*)d_in[3];
  const float* bq = (const float*)d_in[4];
  const float* Wk = (const float*)d_in[5];
  const float* bk = (const float*)d_in[6];
  const float* Wv = (const float*)d_in[7];
  const float* bv = (const float*)d_in[8];
  const float* Wo = (const float*)d_in[9];
  const float* bo = (const float*)d_in[10];

  unsigned short* ws = (unsigned short*)d_ws;
  const size_t SZ  = (size_t)8192 * 1024;
  const size_t WSZ = (size_t)1024 * 1024;
  unsigned short* Xq  = ws;            // Xq,Xk,Xv contiguous (TRIPLE A base)
  unsigned short* Wqb = Xq + 3 * SZ;   // Wq,Wk,Wv,Wo contiguous
  unsigned short* Qp  = Wqb + 4 * WSZ; // Qp,Kp,Vp contiguous (TRIPLE C base)
  unsigned short* Kp  = Qp + SZ;
  unsigned short* Vp  = Kp + SZ;
  unsigned short* Wob = Wqb + 3 * WSZ;
  unsigned short* At  = Xq;            // Xq dead after projections -> reuse

  cvt_all<<<(3 * BIGU + 4 * WU) / 256, 256, 0, stream>>>(q, k, v, Wq, Wk, Wv, Wo, (ushort4*)ws);

  gemm_bt<false, true><<<dim3(GN / 128, GM / 128, 3), 256, 0, stream>>>(Xq, Wqb, bq, bk, bv, Qp);

  attn_fwd<<<dim3(16, 64), 256, 0, stream>>>(Qp, Kp, Vp, At);

  gemm_bt<true, false><<<dim3(GN / 128, GM / 128, 1), 256, 0, stream>>>(At, Wob, bo, bo, bo, (float*)d_out);
}

// Round 7
// 322.438 us; speedup vs baseline: 1.0836x; 1.0836x over previous
//
#include <hip/hip_runtime.h>
#include <stdint.h>

typedef __bf16 bf16x8 __attribute__((ext_vector_type(8)));
typedef __bf16 bf16x4 __attribute__((ext_vector_type(4)));
typedef float f32x4 __attribute__((ext_vector_type(4)));
typedef float f32x16 __attribute__((ext_vector_type(16)));

static __device__ __forceinline__ unsigned short f2bf(float f) {
  unsigned u = __builtin_bit_cast(unsigned, f);
  u += 0x7fffu + ((u >> 16) & 1u);   // RNE
  return (unsigned short)(u >> 16);
}

static __device__ __forceinline__ unsigned short bfu(float x) {
  __bf16 b = (__bf16)x;
  return __builtin_bit_cast(unsigned short, b);
}

static __device__ __forceinline__ unsigned cvtpk(float lo, float hi) {
  unsigned r;
  asm("v_cvt_pk_bf16_f32 %0, %1, %2" : "=v"(r) : "v"(lo), "v"(hi));
  return r;
}

// (x, y) <- swap: x = lane<32 ? a : partner's b ; y = lane<32 ? partner's a : b
static __device__ __forceinline__ void plswap(unsigned a, unsigned b,
                                              unsigned& x, unsigned& y) {
#if __has_builtin(__builtin_amdgcn_permlane32_swap)
  auto r = __builtin_amdgcn_permlane32_swap((int)a, (int)b, false, false);
  x = (unsigned)r[0];
  y = (unsigned)r[1];
#else
  unsigned ap = (unsigned)__shfl_xor((int)a, 32);
  unsigned bp = (unsigned)__shfl_xor((int)b, 32);
  const bool lo = (threadIdx.x & 32) == 0;
  x = lo ? a : bp;
  y = lo ? ap : b;
#endif
}

#if __has_builtin(__builtin_amdgcn_exp2f)
#define EXP2(x) __builtin_amdgcn_exp2f(x)
#else
#define EXP2(x) __expf(0.69314718055994531f * (x))
#endif

static __device__ __forceinline__ void gload_lds16(const void* g, void* l) {
  __builtin_amdgcn_global_load_lds(
      (const __attribute__((address_space(1))) unsigned int*)(uintptr_t)g,
      (__attribute__((address_space(3))) unsigned int*)(uintptr_t)l, 16, 0, 0);
}

// ------------------------- fused fp32 -> bf16 convert (all 7 tensors) ----
#define BIGU 2097152
#define WU   262144
__global__ __launch_bounds__(256) void cvt_all(const float* __restrict__ q,  const float* __restrict__ k,
                                               const float* __restrict__ v,  const float* __restrict__ wq,
                                               const float* __restrict__ wk, const float* __restrict__ wv,
                                               const float* __restrict__ wo, ushort4* __restrict__ dst) {
  int u = blockIdx.x * 256 + threadIdx.x;
  const float4* src;
  if (u < BIGU)            src = (const float4*)q + u;
  else if (u < 2 * BIGU)   src = (const float4*)k + (u - BIGU);
  else if (u < 3 * BIGU)   src = (const float4*)v + (u - 2 * BIGU);
  else {
    int r = u - 3 * BIGU;
    if (r < WU)            src = (const float4*)wq + r;
    else if (r < 2 * WU)   src = (const float4*)wk + (r - WU);
    else if (r < 3 * WU)   src = (const float4*)wv + (r - 2 * WU);
    else                   src = (const float4*)wo + (r - 3 * WU);
  }
  float4 f = *src;
  ushort4 o;
  o.x = f2bf(f.x); o.y = f2bf(f.y); o.z = f2bf(f.z); o.w = f2bf(f.w);
  dst[u] = o;
}

// ------------------------- GEMM: C[M,N] = A[M,K] @ W[N,K]^T + bias ------
// 128x128 tile, BK=64, 2-phase double-buffered prefetch, bijective chunked
// XCD swizzle (T1/m204): XCD k owns a contiguous x-major chunk so the 8
// blocks sharing an A-panel hit the same per-XCD L2.
#define GM 8192
#define GN 1024
#define GK 1024

template <bool OUTF32, bool TRIPLE>
__global__ __launch_bounds__(256, 2) void gemm_bt(const unsigned short* __restrict__ A0,
                                                  const unsigned short* __restrict__ W0,
                                                  const float* __restrict__ bias0,
                                                  const float* __restrict__ bias1,
                                                  const float* __restrict__ bias2,
                                                  void* __restrict__ Cout) {
  __shared__ unsigned short As[2][128 * 64];
  __shared__ unsigned short Bs[2][128 * 64];

  // ---- T1 bijective chunked XCD swizzle (NWG % 8 == 0 for both shapes)
  const int NXB = GN / 128;                       // 8
  const int NYB = GM / 128;                       // 64
  const int NWG = NXB * NYB * (TRIPLE ? 3 : 1);   // 1536 / 512
  int bid = blockIdx.x + NXB * (blockIdx.y + NYB * blockIdx.z);
  int swz = (bid & 7) * (NWG >> 3) + (bid >> 3);
  const int z = TRIPLE ? (swz / (NXB * NYB)) : 0;
  const int rem = swz - z * NXB * NYB;
  const int bm = (rem >> 3) * 128;                // rem / NXB
  const int bn = (rem & 7) * 128;                 // rem % NXB

  const unsigned short* A  = A0 + (size_t)z * ((size_t)GM * GK);
  const unsigned short* Bw = W0 + (size_t)z * ((size_t)GN * GK);
  const float* bias = TRIPLE ? (z == 0 ? bias0 : (z == 1 ? bias1 : bias2)) : bias0;

  const int tid = threadIdx.x;
  const int w = tid >> 6;
  const int lane = tid & 63;
  const int lq = lane & 15;
  const int g = lane >> 4;
  const int srow = lane >> 3;
  const int schunk = (lane & 7) ^ srow;
  const int wrow = (w >> 1) * 64;
  const int wcol = (w & 1) * 64;

  f32x4 acc[4][4] = {};

#define STAGE(ktv, bufv)                                                                   \
  do {                                                                                     \
    _Pragma("unroll") for (int j = 0; j < 4; ++j) {                                        \
      const int r0 = w * 32 + j * 8;                                                       \
      gload_lds16(A  + (size_t)(bm + r0 + srow) * GK + (ktv) * 64 + schunk * 8,            \
                  &As[bufv][r0 * 64]);                                                     \
      gload_lds16(Bw + (size_t)(bn + r0 + srow) * GK + (ktv) * 64 + schunk * 8,            \
                  &Bs[bufv][r0 * 64]);                                                     \
    }                                                                                      \
  } while (0)

  STAGE(0, 0);
  __syncthreads();

  for (int kt = 0; kt < GK / 64; ++kt) {
    const int cur = kt & 1;
    if (kt < GK / 64 - 1) STAGE(kt + 1, cur ^ 1);

#pragma unroll
    for (int kk = 0; kk < 2; ++kk) {
      bf16x8 af[4], bfv[4];
#pragma unroll
      for (int mt = 0; mt < 4; ++mt) {
        int m = wrow + mt * 16 + lq;
        af[mt] = *(const bf16x8*)&As[cur][m * 64 + ((kk * 32 + g * 8) ^ ((m & 7) << 3))];
      }
#pragma unroll
      for (int nt = 0; nt < 4; ++nt) {
        int n = wcol + nt * 16 + lq;
        bfv[nt] = *(const bf16x8*)&Bs[cur][n * 64 + ((kk * 32 + g * 8) ^ ((n & 7) << 3))];
      }
#pragma unroll
      for (int mt = 0; mt < 4; ++mt)
#pragma unroll
        for (int nt = 0; nt < 4; ++nt)
          acc[mt][nt] = __builtin_amdgcn_mfma_f32_16x16x32_bf16(af[mt], bfv[nt], acc[mt][nt], 0, 0, 0);
    }
    __syncthreads();
  }
#undef STAGE

  float bvs[4];
#pragma unroll
  for (int nt = 0; nt < 4; ++nt) bvs[nt] = bias[bn + wcol + nt * 16 + lq];

#pragma unroll
  for (int mt = 0; mt < 4; ++mt) {
#pragma unroll
    for (int nt = 0; nt < 4; ++nt) {
#pragma unroll
      for (int r = 0; r < 4; ++r) {
        int m = bm + wrow + mt * 16 + g * 4 + r;
        int n = bn + wcol + nt * 16 + lq;
        float v = acc[mt][nt][r] + bvs[nt];
        if (OUTF32) ((float*)Cout)[(size_t)m * GN + n] = v;
        else ((unsigned short*)Cout)[(size_t)z * ((size_t)GM * GN) + (size_t)m * GN + n] = f2bf(v);
      }
    }
  }
}

// ------------------------- flash attention v4: 32x32 MFMA, in-reg softmax -
#define TRRD(dst, off) \
  asm volatile("ds_read_b64_tr_b16 %0, %1 offset:" off \
               : "=v"(dst) \
               : "v"((const __attribute__((address_space(3))) unsigned short*)(uintptr_t)vb))

__global__ __launch_bounds__(256, 4) void attn_fwd(const unsigned short* __restrict__ Qp,
                                                   const unsigned short* __restrict__ Kp,
                                                   const unsigned short* __restrict__ Vp,
                                                   unsigned short* __restrict__ Op) {
  __shared__ unsigned short Ks[2][4096];    // [key][d] row-swizzled, 8KB each
  __shared__ unsigned short Vs[2][4096];    // [key/4][d/16][4][16] subtiled
  const int tid = threadIdx.x;
  const int w = tid >> 6;
  const int lane = tid & 63;
  const int q32 = lane & 31;
  const int l5 = lane >> 5;
  const int qt = blockIdx.x;
  const int bh = blockIdx.y;
  const int b = bh >> 4;
  const int h = bh & 15;
  const size_t rowbase = (size_t)b * 2048;
  const int hcol = h * 64;

  const int c0 = w * 2, c1 = w * 2 + 1;
  const int srow = lane >> 3;
  const int schunk = (lane & 7) ^ srow;
  const int vkeyl = (lane >> 5) * 4 + ((lane >> 1) & 3);
  const int vd0   = ((lane >> 3) & 3) * 16 + (lane & 1) * 8;

  const unsigned short* kq = Kp + rowbase * 1024 + hcol;
  const unsigned short* vq = Vp + rowbase * 1024 + hcol;

  // per-thread incremental staging pointers (tile 0 bases)
  const unsigned short* kgA = kq + (size_t)(c0 * 8 + srow) * 1024 + schunk * 8;
  const unsigned short* kgB = kq + (size_t)(c1 * 8 + srow) * 1024 + schunk * 8;
  const unsigned short* vgA = vq + (size_t)(c0 * 8 + vkeyl) * 1024 + vd0;
  const unsigned short* vgB = vq + (size_t)(c1 * 8 + vkeyl) * 1024 + vd0;

  // Q B-fragments: lane = (col q, k-rows ks*16 + l5*8 .. +7)
  const int qrow = qt * 128 + w * 32 + q32;
  bf16x8 qf[4];
#pragma unroll
  for (int ks = 0; ks < 4; ++ks)
    qf[ks] = *(const bf16x8*)&Qp[(rowbase + qrow) * 1024 + hcol + ks * 16 + l5 * 8];

  const float ks2 = 0.125f * 1.44269504088896f;  // scale * log2(e)
  float mreg = -1e30f, lsum = 0.f;
  f32x16 oa[2] = {};                             // O^T: dt -> d = dt*32 + C-row, q = q32

  const int rbase = q32 * 64;
  const int kxor = (lane & 7) << 3;
  int coff[4];
#pragma unroll
  for (int ks = 0; ks < 4; ++ks) coff[ks] = (ks * 16 + l5 * 8) ^ kxor;
  const int vboff = l5 * 512 + ((lane >> 4) & 1) * 64 + ((lane >> 2) & 3) * 16 + (lane & 3) * 4;

  // prologue: stage tile 0 into buf 0
  gload_lds16(kgA, &Ks[0][c0 * 512]);
  gload_lds16(kgB, &Ks[0][c1 * 512]);
  gload_lds16(vgA, &Vs[0][c0 * 512]);
  gload_lds16(vgB, &Vs[0][c1 * 512]);
  __syncthreads();

  for (int j = 0; j < 32; ++j) {
    const int cur = j & 1;
    if (j < 31) {   // prefetch next tile into other buffer (advance 64 rows)
      kgA += 65536; kgB += 65536; vgA += 65536; vgB += 65536;
      gload_lds16(kgA, &Ks[cur ^ 1][c0 * 512]);
      gload_lds16(kgB, &Ks[cur ^ 1][c1 * 512]);
      gload_lds16(vgA, &Vs[cur ^ 1][c0 * 512]);
      gload_lds16(vgB, &Vs[cur ^ 1][c1 * 512]);
    }

#pragma unroll
    for (int kt = 0; kt < 2; ++kt) {
      // ---- QK^T: S^T[key 32][q 32] = sum_ks mfma(K-frag, Q-frag)
      f32x16 c = {};
      __builtin_amdgcn_s_setprio(1);
#pragma unroll
      for (int ks = 0; ks < 4; ++ks) {
        bf16x8 kf = *(const bf16x8*)&Ks[cur][kt * 2048 + rbase + coff[ks]];
        c = __builtin_amdgcn_mfma_f32_32x32x16_bf16(kf, qf[ks], c, 0, 0, 0);
      }
      __builtin_amdgcn_s_setprio(0);

      // ---- V^T fragments via hw transpose read (issue early, wait later)
      const unsigned short* vb = &Vs[cur][kt * 2048 + vboff];
      bf16x4 T[8];
      TRRD(T[0], "0");    TRRD(T[1], "512");
      TRRD(T[2], "256");  TRRD(T[3], "768");
      TRRD(T[4], "2048"); TRRD(T[5], "2560");
      TRRD(T[6], "2304"); TRRD(T[7], "2816");

      // ---- row-max over this 32-key chunk (regs + partner lane)
      float a0 = fmaxf(c[0], c[1]),   a1 = fmaxf(c[2], c[3]);
      float a2 = fmaxf(c[4], c[5]),   a3 = fmaxf(c[6], c[7]);
      float a4 = fmaxf(c[8], c[9]),   a5 = fmaxf(c[10], c[11]);
      float a6 = fmaxf(c[12], c[13]), a7 = fmaxf(c[14], c[15]);
      a0 = fmaxf(a0, a1); a2 = fmaxf(a2, a3); a4 = fmaxf(a4, a5); a6 = fmaxf(a6, a7);
      a0 = fmaxf(a0, a2); a4 = fmaxf(a4, a6);
      float tm = fmaxf(a0, a4);
      tm = fmaxf(tm, __shfl_xor(tm, 32));

      // ---- defer-max (THR=64 raw == 8 scaled)
      if (!__all(tm - mreg <= 64.f)) {
        float n = fmaxf(mreg, tm);
        float cr = EXP2(ks2 * (mreg - n));
        lsum *= cr;
        oa[0] *= cr; oa[1] *= cr;
        mreg = n;
      }
      const float mk = mreg * ks2;
      float p[16];
#pragma unroll
      for (int r = 0; r < 16; ++r) p[r] = EXP2(__builtin_fmaf(c[r], ks2, -mk));
      float s0 = (p[0] + p[1]) + (p[2] + p[3]);
      float s1 = (p[4] + p[5]) + (p[6] + p[7]);
      float s2 = (p[8] + p[9]) + (p[10] + p[11]);
      float s3 = (p[12] + p[13]) + (p[14] + p[15]);
      lsum += (s0 + s1) + (s2 + s3);

      asm volatile("s_waitcnt lgkmcnt(0)" ::: "memory");
      __builtin_amdgcn_sched_barrier(0);

      // ---- pack P -> B-frag (cvt_pk + permlane32_swap) and PV MFMA
      __builtin_amdgcn_s_setprio(1);
#pragma unroll
      for (int t2 = 0; t2 < 2; ++t2) {
        unsigned pA0 = cvtpk(p[8 * t2 + 0], p[8 * t2 + 1]);
        unsigned pA1 = cvtpk(p[8 * t2 + 2], p[8 * t2 + 3]);
        unsigned pB0 = cvtpk(p[8 * t2 + 4], p[8 * t2 + 5]);
        unsigned pB1 = cvtpk(p[8 * t2 + 6], p[8 * t2 + 7]);
        unsigned w0, w1, w2, w3;
        plswap(pA0, pB0, w0, w2);
        plswap(pA1, pB1, w1, w3);
        uint4 wv; wv.x = w0; wv.y = w1; wv.z = w2; wv.w = w3;
        bf16x8 pf = __builtin_bit_cast(bf16x8, wv);
        bf16x8 vf0 = __builtin_shufflevector(T[t2 * 4 + 0], T[t2 * 4 + 1], 0, 1, 2, 3, 4, 5, 6, 7);
        oa[0] = __builtin_amdgcn_mfma_f32_32x32x16_bf16(vf0, pf, oa[0], 0, 0, 0);
        bf16x8 vf1 = __builtin_shufflevector(T[t2 * 4 + 2], T[t2 * 4 + 3], 0, 1, 2, 3, 4, 5, 6, 7);
        oa[1] = __builtin_amdgcn_mfma_f32_32x32x16_bf16(vf1, pf, oa[1], 0, 0, 0);
      }
      __builtin_amdgcn_s_setprio(0);
    }
    __syncthreads();
  }

  // ---- epilogue
  lsum += __shfl_xor(lsum, 32);
  const float inv = 1.0f / lsum;
#pragma unroll
  for (int dt = 0; dt < 2; ++dt) {
#pragma unroll
    for (int jj = 0; jj < 4; ++jj) {
      ushort4 pk;
      pk.x = bfu(oa[dt][4 * jj + 0] * inv);
      pk.y = bfu(oa[dt][4 * jj + 1] * inv);
      pk.z = bfu(oa[dt][4 * jj + 2] * inv);
      pk.w = bfu(oa[dt][4 * jj + 3] * inv);
      const int d0 = dt * 32 + 8 * jj + 4 * l5;
      *(ushort4*)&Op[(rowbase + qrow) * 1024 + hcol + d0] = pk;
    }
  }
}

// ------------------------- launcher --------------------------------------
extern "C" void kernel_launch(void* const* d_in, const int* in_sizes, int n_in,
                              void* d_out, int out_size, void* d_ws, size_t ws_size,
                              hipStream_t stream) {
  const float* q  = (const float*)d_in[0];
  const float* k  = (const float*)d_in[1];
  const float* v  = (const float*)d_in[2];
  const float* Wq = (const float*)d_in[3];
  const float* bq = (const float*)d_in[4];
  const float* Wk = (const float*)d_in[5];
  const float* bk = (const float*)d_in[6];
  const float* Wv = (const float*)d_in[7];
  const float* bv = (const float*)d_in[8];
  const float* Wo = (const float*)d_in[9];
  const float* bo = (const float*)d_in[10];

  unsigned short* ws = (unsigned short*)d_ws;
  const size_t SZ  = (size_t)8192 * 1024;
  const size_t WSZ = (size_t)1024 * 1024;
  unsigned short* Xq  = ws;            // Xq,Xk,Xv contiguous (TRIPLE A base)
  unsigned short* Wqb = Xq + 3 * SZ;   // Wq,Wk,Wv,Wo contiguous
  unsigned short* Qp  = Wqb + 4 * WSZ; // Qp,Kp,Vp contiguous (TRIPLE C base)
  unsigned short* Kp  = Qp + SZ;
  unsigned short* Vp  = Kp + SZ;
  unsigned short* Wob = Wqb + 3 * WSZ;
  unsigned short* At  = Xq;            // Xq dead after projections -> reuse

  cvt_all<<<(3 * BIGU + 4 * WU) / 256, 256, 0, stream>>>(q, k, v, Wq, Wk, Wv, Wo, (ushort4*)ws);

  gemm_bt<false, true><<<dim3(GN / 128, GM / 128, 3), 256, 0, stream>>>(Xq, Wqb, bq, bk, bv, Qp);

  attn_fwd<<<dim3(16, 64), 256, 0, stream>>>(Qp, Kp, Vp, At);

  gemm_bt<true, false><<<dim3(GN / 128, GM / 128, 1), 256, 0, stream>>>(At, Wob, bo, bo, bo, (float*)d_out);
}